// Round 11
// baseline (3188.592 us; speedup 1.0000x reference)
//
#include <hip/hip_runtime.h>

#define BB 64
#define SS 1024
#define HH 512

typedef short short8 __attribute__((ext_vector_type(8)));
typedef float f32x4 __attribute__((ext_vector_type(4)));
typedef _Float16 h2 __attribute__((ext_vector_type(2)));

__device__ inline unsigned short f2bf(float f) {
  unsigned int u = __builtin_bit_cast(unsigned int, f);
  u += 0x7fffu + ((u >> 16) & 1u);   // round-to-nearest-even
  return (unsigned short)(u >> 16);
}

__device__ inline unsigned int pack_h2(float a, float b) {
  unsigned short ua = __builtin_bit_cast(unsigned short, (_Float16)a);
  unsigned short ub = __builtin_bit_cast(unsigned short, (_Float16)b);
  return (unsigned int)ua | ((unsigned int)ub << 16);
}

__device__ inline float dot2a(unsigned int w, unsigned int h, float acc) {
#if __has_builtin(__builtin_amdgcn_fdot2)
  return __builtin_amdgcn_fdot2(__builtin_bit_cast(h2, w),
                                __builtin_bit_cast(h2, h), acc, false);
#else
  h2 a = __builtin_bit_cast(h2, w);
  h2 b = __builtin_bit_cast(h2, h);
  return acc + (float)a[0] * (float)b[0] + (float)a[1] * (float)b[1];
#endif
}

// ---------------------------------------------------------------------------
// Phase 0: pack W_hh rows 192..511 (streamed groups) as f16 into d_ws,
// [L][t] layout so per-step stream loads are coalesced dwordx4.
// L = gs*8 + c (gs=0..4): thread t (kg=t>>6, hg=t&63) packs
// row hg+64*(3+gs), k-chunk kg*64 + c*8.
// ---------------------------------------------------------------------------
__global__ __launch_bounds__(512) void pack_ws(
    const float* __restrict__ Whh, uint4* __restrict__ ws4) {
  const int L = blockIdx.x;        // 0..39
  const int t = threadIdx.x;       // 0..511
  const int kg = t >> 6, hg = t & 63;
  const int row = hg + 64 * (3 + (L >> 3));
  const int k0 = kg * 64 + (L & 7) * 8;
  const float* p = Whh + (size_t)row * HH + k0;
  float4 f0 = ((const float4*)p)[0];
  float4 f1 = ((const float4*)p)[1];
  uint4 v;
  v.x = pack_h2(f0.x, f0.y); v.y = pack_h2(f0.z, f0.w);
  v.z = pack_h2(f1.x, f1.y); v.w = pack_h2(f1.z, f1.w);
  ws4[(size_t)L * 512 + t] = v;    // coalesced 16B/lane store
}

// ---------------------------------------------------------------------------
// Phase 1: xt[m, n] = sum_k x[m,k] * W_ih[n,k] + b_ih[n]  (unchanged)
// ---------------------------------------------------------------------------
__global__ __launch_bounds__(256) void xt_gemm(
    const float* __restrict__ x, const float* __restrict__ Wih,
    const float* __restrict__ bih, float* __restrict__ out) {
  __shared__ unsigned short As[64][56];
  __shared__ unsigned short Bs[64][56];

  const int bn = blockIdx.x;  // 0..7
  const int bm = blockIdx.y;  // 0..1023
  const int t = threadIdx.x;
  const int wave = t >> 6, lane = t & 63;
  const int wm = wave >> 1, wn = wave & 1;
  const int m_base = bm * 64, n_base = bn * 64;
  const int sr = t >> 2;
  const int sc = (t & 3) * 8;

  f32x4 acc[2][2] = {};

  for (int k0 = 0; k0 < 512; k0 += 32) {
    __syncthreads();
    {
      const float* p = x + (size_t)(m_base + sr) * 512 + k0 + sc;
      float4 v0 = *(const float4*)p;
      float4 v1 = *(const float4*)(p + 4);
      short8 sa;
      sa[0] = (short)f2bf(v0.x); sa[1] = (short)f2bf(v0.y);
      sa[2] = (short)f2bf(v0.z); sa[3] = (short)f2bf(v0.w);
      sa[4] = (short)f2bf(v1.x); sa[5] = (short)f2bf(v1.y);
      sa[6] = (short)f2bf(v1.z); sa[7] = (short)f2bf(v1.w);
      *(short8*)&As[sr][sc] = sa;

      const float* q = Wih + (size_t)(n_base + sr) * 512 + k0 + sc;
      float4 w0 = *(const float4*)q;
      float4 w1 = *(const float4*)(q + 4);
      short8 sb;
      sb[0] = (short)f2bf(w0.x); sb[1] = (short)f2bf(w0.y);
      sb[2] = (short)f2bf(w0.z); sb[3] = (short)f2bf(w0.w);
      sb[4] = (short)f2bf(w1.x); sb[5] = (short)f2bf(w1.y);
      sb[6] = (short)f2bf(w1.z); sb[7] = (short)f2bf(w1.w);
      *(short8*)&Bs[sr][sc] = sb;
    }
    __syncthreads();

    const int kq = (lane >> 4) * 8;
    short8 a0 = *(const short8*)&As[wm * 32 + (lane & 15)][kq];
    short8 a1 = *(const short8*)&As[wm * 32 + 16 + (lane & 15)][kq];
    short8 b0 = *(const short8*)&Bs[wn * 32 + (lane & 15)][kq];
    short8 b1 = *(const short8*)&Bs[wn * 32 + 16 + (lane & 15)][kq];
    acc[0][0] = __builtin_amdgcn_mfma_f32_16x16x32_bf16(a0, b0, acc[0][0], 0, 0, 0);
    acc[0][1] = __builtin_amdgcn_mfma_f32_16x16x32_bf16(a0, b1, acc[0][1], 0, 0, 0);
    acc[1][0] = __builtin_amdgcn_mfma_f32_16x16x32_bf16(a1, b0, acc[1][0], 0, 0, 0);
    acc[1][1] = __builtin_amdgcn_mfma_f32_16x16x32_bf16(a1, b1, acc[1][1], 0, 0, 0);
  }

#pragma unroll
  for (int ni = 0; ni < 2; ++ni) {
    const int gcol = n_base + wn * 32 + ni * 16 + (lane & 15);
    const float bv = bih[gcol];
#pragma unroll
    for (int mi = 0; mi < 2; ++mi) {
#pragma unroll
      for (int j = 0; j < 4; ++j) {
        const int grow = m_base + wm * 32 + mi * 16 + (lane >> 4) * 4 + j;
        out[(size_t)grow * 512 + gcol] = acc[mi][ni][j] + bv;
      }
    }
  }
}

// ---------------------------------------------------------------------------
// Phase 2: per-batch scan, 512 threads. Storage (proven no-spill budget):
//   groups 0,1 in regs (64 dw), group 2 in LDS (64 KB), groups 3..7 streamed
//   (320 KB/step) via a RING-8 of uint4 buffers: consume-1/issue-1 per
//   unrolled iteration -> in-flight stays ~8 loads/wave (~64 KB/CU) for the
//   whole stream phase (Little: ~260 B/cyc), vs R10's 2-batch lookahead
//   (64 cyc << 250-cyc L2 latency -> ~1500 cyc/step of vmcnt stalls).
//   Prologue loads issue BEFORE the reg/LDS dot phase (fill latency hidden).
// LDS padded >80 KB so only 1 WG/CU fits (protects the 128-VGPR regime).
// ---------------------------------------------------------------------------
__global__
__attribute__((amdgpu_flat_work_group_size(512, 512)))
void rnn_scan(const float* __restrict__ Whh, const float* __restrict__ bhh,
              float* __restrict__ out, float* __restrict__ last,
              const uint4* __restrict__ ws4) {
  __shared__ uint4 wlds[8 * 512];         // 64 KB: W row-group 2
  __shared__ float part[8 * 512];         // 16 KB partials
  __shared__ unsigned short hbuf[512];    // 1 KB h state (f16)
  __shared__ unsigned int lds_pad[4096];  // 16 KB pad -> 97 KB: force 1 WG/CU

  const int b = blockIdx.x;
  const int t = threadIdx.x;
  const int kg = t >> 6;        // 0..7, wave-uniform
  const int hg = t & 63;
  const int k0 = kg * 64;
  if (b == 0x7fffffff) lds_pad[t] = 0;  // keep pad alive, never executes

  // --- one-time: row-groups 0,1 into regs ---
  unsigned int wreg[2][32];
#pragma unroll
  for (int i = 0; i < 2; ++i) {
    const float* wr = Whh + (size_t)(hg + 64 * i) * 512 + k0;
#pragma unroll
    for (int c4 = 0; c4 < 16; ++c4) {
      float4 f = ((const float4*)wr)[c4];
      wreg[i][c4 * 2]     = pack_h2(f.x, f.y);
      wreg[i][c4 * 2 + 1] = pack_h2(f.z, f.w);
    }
  }
  // --- one-time: row-group 2 into LDS ---
  {
    const float* wr = Whh + (size_t)(hg + 128) * 512 + k0;
#pragma unroll
    for (int c = 0; c < 8; ++c) {
      float4 f0 = ((const float4*)wr)[c * 2];
      float4 f1 = ((const float4*)wr)[c * 2 + 1];
      uint4 v;
      v.x = pack_h2(f0.x, f0.y); v.y = pack_h2(f0.z, f0.w);
      v.z = pack_h2(f1.x, f1.y); v.w = pack_h2(f1.z, f1.w);
      wlds[c * 512 + t] = v;
    }
  }
  if (t < 256) ((unsigned int*)hbuf)[t] = 0;  // h_0 = 0

  float* xt_row = out + (size_t)b * SS * HH;
  float xt_cur = xt_row[t];
  const float bh = bhh[t];
  const uint4* h4 = (const uint4*)hbuf + kg * 8;
  const uint4* wsp = ws4 + t;
  __syncthreads();

  for (int step = 0; step < SS; ++step) {
    // prefetch next xt (consumed in finalize next iteration)
    float xt_next = 0.f;
    if (step + 1 < SS) xt_next = xt_row[(size_t)(step + 1) * HH + t];

    // --- stream prologue: fill ring-8 (in flight during reg/LDS phase) ---
    uint4 bufs[8];
#pragma unroll
    for (int j = 0; j < 8; ++j) bufs[j] = wsp[j * 512];

    float acc_[8] = {0.f, 0.f, 0.f, 0.f, 0.f, 0.f, 0.f, 0.f};

    // --- reg/LDS dot phase: groups 0,1 (regs) + group 2 (LDS) ---
#pragma unroll
    for (int c = 0; c < 8; ++c) {
      uint4 hv = h4[c];                  // wave-uniform -> broadcast
      uint4 wl = wlds[c * 512 + t];      // conflict-free b128
      acc_[0] = dot2a(wreg[0][4 * c + 0], hv.x, acc_[0]);
      acc_[0] = dot2a(wreg[0][4 * c + 1], hv.y, acc_[0]);
      acc_[0] = dot2a(wreg[0][4 * c + 2], hv.z, acc_[0]);
      acc_[0] = dot2a(wreg[0][4 * c + 3], hv.w, acc_[0]);
      acc_[1] = dot2a(wreg[1][4 * c + 0], hv.x, acc_[1]);
      acc_[1] = dot2a(wreg[1][4 * c + 1], hv.y, acc_[1]);
      acc_[1] = dot2a(wreg[1][4 * c + 2], hv.z, acc_[1]);
      acc_[1] = dot2a(wreg[1][4 * c + 3], hv.w, acc_[1]);
      acc_[2] = dot2a(wl.x, hv.x, acc_[2]);
      acc_[2] = dot2a(wl.y, hv.y, acc_[2]);
      acc_[2] = dot2a(wl.z, hv.z, acc_[2]);
      acc_[2] = dot2a(wl.w, hv.w, acc_[2]);
    }

    // --- stream loop: 40 iters, ring-8, consume-1 / issue-1 ---
    // iter i: group gs=i>>3 (acc_[3+gs]), chunk c=i&7 (h4[c]), slot i&7.
#pragma unroll
    for (int i = 0; i < 40; ++i) {
      uint4 hv = h4[i & 7];
      uint4 w = bufs[i & 7];
      const int ai = 3 + (i >> 3);
      acc_[ai] = dot2a(w.x, hv.x, acc_[ai]);
      acc_[ai] = dot2a(w.y, hv.y, acc_[ai]);
      acc_[ai] = dot2a(w.z, hv.z, acc_[ai]);
      acc_[ai] = dot2a(w.w, hv.w, acc_[ai]);
      if (i < 32) bufs[i & 7] = wsp[(i + 8) * 512];
    }

    // partial store: per wave, 64 consecutive dwords per group
#pragma unroll
    for (int i = 0; i < 8; ++i) part[kg * 512 + hg + 64 * i] = acc_[i];
    __syncthreads();

    // finalize: all 512 threads, h = t
    float y = xt_cur + bh;
#pragma unroll
    for (int g = 0; g < 8; ++g) y += part[g * 512 + t];
    float ht = tanhf(y);
    xt_row[(size_t)step * HH + t] = ht;  // overwrite xt with output h
    hbuf[t] = __builtin_bit_cast(unsigned short, (_Float16)ht);
    xt_cur = xt_next;
    __syncthreads();
  }

  last[(size_t)b * HH + t] = xt_row[(size_t)(SS - 1) * HH + t];
}

extern "C" void kernel_launch(void* const* d_in, const int* in_sizes, int n_in,
                              void* d_out, int out_size, void* d_ws, size_t ws_size,
                              hipStream_t stream) {
  (void)in_sizes; (void)n_in; (void)ws_size; (void)out_size;
  const float* x   = (const float*)d_in[0];
  const float* Wih = (const float*)d_in[1];
  const float* bih = (const float*)d_in[2];
  const float* Whh = (const float*)d_in[3];
  const float* bhh = (const float*)d_in[4];
  float* out  = (float*)d_out;
  float* last = out + (size_t)BB * SS * HH;
  uint4* ws4  = (uint4*)d_ws;   // 320 KB: pre-packed f16 stream layout

  // Phase 0: pack streamed W rows (f16, [L][t] coalesced layout)
  pack_ws<<<40, 512, 0, stream>>>(Whh, ws4);

  // Phase 1: input projection for all timesteps -> d_out (in-place xt buffer)
  xt_gemm<<<dim3(8, 1024), 256, 0, stream>>>(x, Wih, bih, out);

  // Phase 2: 64 sync-free per-batch chains
  rnn_scan<<<64, 512, 0, stream>>>(Whh, bhh, out, last, ws4);
}

// Round 12
// 3084.731 us; speedup vs baseline: 1.0337x; 1.0337x over previous
//
#include <hip/hip_runtime.h>

#define BB 64
#define SS 1024
#define HH 512

typedef short short8 __attribute__((ext_vector_type(8)));
typedef float f32x4 __attribute__((ext_vector_type(4)));
typedef _Float16 h2 __attribute__((ext_vector_type(2)));

__device__ inline unsigned short f2bf(float f) {
  unsigned int u = __builtin_bit_cast(unsigned int, f);
  u += 0x7fffu + ((u >> 16) & 1u);   // round-to-nearest-even
  return (unsigned short)(u >> 16);
}

__device__ inline unsigned int pack_h2(float a, float b) {
  unsigned short ua = __builtin_bit_cast(unsigned short, (_Float16)a);
  unsigned short ub = __builtin_bit_cast(unsigned short, (_Float16)b);
  return (unsigned int)ua | ((unsigned int)ub << 16);
}

__device__ inline float dot2a(unsigned int w, unsigned int h, float acc) {
#if __has_builtin(__builtin_amdgcn_fdot2)
  return __builtin_amdgcn_fdot2(__builtin_bit_cast(h2, w),
                                __builtin_bit_cast(h2, h), acc, false);
#else
  h2 a = __builtin_bit_cast(h2, w);
  h2 b = __builtin_bit_cast(h2, h);
  return acc + (float)a[0] * (float)b[0] + (float)a[1] * (float)b[1];
#endif
}

// ---------------------------------------------------------------------------
// Phase 1: xt[m, n] = sum_k x[m,k] * W_ih[n,k] + b_ih[n],  m = b*S + s
// bf16 MFMA 16x16x32, BM=BN=64, BK=32, 256 threads (4 waves, 2x2 wave grid).
// Writes fp32 into d_out[0 : B*S*H]; phase 2 overwrites in place.
// ---------------------------------------------------------------------------
__global__ __launch_bounds__(256) void xt_gemm(
    const float* __restrict__ x, const float* __restrict__ Wih,
    const float* __restrict__ bih, float* __restrict__ out) {
  __shared__ unsigned short As[64][56];
  __shared__ unsigned short Bs[64][56];

  const int bn = blockIdx.x;  // 0..7
  const int bm = blockIdx.y;  // 0..1023
  const int t = threadIdx.x;
  const int wave = t >> 6, lane = t & 63;
  const int wm = wave >> 1, wn = wave & 1;
  const int m_base = bm * 64, n_base = bn * 64;
  const int sr = t >> 2;        // staging row 0..63
  const int sc = (t & 3) * 8;   // staging col chunk 0,8,16,24

  f32x4 acc[2][2] = {};

  for (int k0 = 0; k0 < 512; k0 += 32) {
    __syncthreads();
    {
      const float* p = x + (size_t)(m_base + sr) * 512 + k0 + sc;
      float4 v0 = *(const float4*)p;
      float4 v1 = *(const float4*)(p + 4);
      short8 sa;
      sa[0] = (short)f2bf(v0.x); sa[1] = (short)f2bf(v0.y);
      sa[2] = (short)f2bf(v0.z); sa[3] = (short)f2bf(v0.w);
      sa[4] = (short)f2bf(v1.x); sa[5] = (short)f2bf(v1.y);
      sa[6] = (short)f2bf(v1.z); sa[7] = (short)f2bf(v1.w);
      *(short8*)&As[sr][sc] = sa;

      const float* q = Wih + (size_t)(n_base + sr) * 512 + k0 + sc;
      float4 w0 = *(const float4*)q;
      float4 w1 = *(const float4*)(q + 4);
      short8 sb;
      sb[0] = (short)f2bf(w0.x); sb[1] = (short)f2bf(w0.y);
      sb[2] = (short)f2bf(w0.z); sb[3] = (short)f2bf(w0.w);
      sb[4] = (short)f2bf(w1.x); sb[5] = (short)f2bf(w1.y);
      sb[6] = (short)f2bf(w1.z); sb[7] = (short)f2bf(w1.w);
      *(short8*)&Bs[sr][sc] = sb;
    }
    __syncthreads();

    const int kq = (lane >> 4) * 8;  // k-chunk within BK
    short8 a0 = *(const short8*)&As[wm * 32 + (lane & 15)][kq];
    short8 a1 = *(const short8*)&As[wm * 32 + 16 + (lane & 15)][kq];
    short8 b0 = *(const short8*)&Bs[wn * 32 + (lane & 15)][kq];
    short8 b1 = *(const short8*)&Bs[wn * 32 + 16 + (lane & 15)][kq];
    acc[0][0] = __builtin_amdgcn_mfma_f32_16x16x32_bf16(a0, b0, acc[0][0], 0, 0, 0);
    acc[0][1] = __builtin_amdgcn_mfma_f32_16x16x32_bf16(a0, b1, acc[0][1], 0, 0, 0);
    acc[1][0] = __builtin_amdgcn_mfma_f32_16x16x32_bf16(a1, b0, acc[1][0], 0, 0, 0);
    acc[1][1] = __builtin_amdgcn_mfma_f32_16x16x32_bf16(a1, b1, acc[1][1], 0, 0, 0);
  }

  // C/D layout (m89-verified): col = lane&15 (N), row = (lane>>4)*4 + j (M)
#pragma unroll
  for (int ni = 0; ni < 2; ++ni) {
    const int gcol = n_base + wn * 32 + ni * 16 + (lane & 15);
    const float bv = bih[gcol];
#pragma unroll
    for (int mi = 0; mi < 2; ++mi) {
#pragma unroll
      for (int j = 0; j < 4; ++j) {
        const int grow = m_base + wm * 32 + mi * 16 + (lane >> 4) * 4 + j;
        out[(size_t)grow * 512 + gcol] = acc[mi][ni][j] + bv;
      }
    }
  }
}

// ---------------------------------------------------------------------------
// Phase 2: per-batch scan, one WG (512 threads, 8 waves) per chain.
// R12 experiment (single variable vs R5): ALL 8 row-groups requested in
// registers (256 dw/thread, asm-pinned); ZERO LDS weight storage. The
// allocator keeps ~98 hottest dwords and spills the rest to scratch — and
// R3/R5 evidence shows compiler-scheduled spill reloads hide under the
// serial VALU+LDS stream, whereas our hand-written streams (R10/R11) did
// not. This removes the 1536-cyc/step LDS weight-read term entirely:
//   serial ≈ dot2 1024 + h-broadcast 256 + finalize/barriers 400 ≈ 1700 cyc
//   hidden ≈ ~316 KB/step spill reload (VMEM)
// LDS = partials + hbuf + 72 KB pad (keeps 1 WG/CU -> 2 waves/SIMD regime).
// Thread t: kg = t>>6 (k-span 64, wave-uniform), hg = t&63; rows hg + 64*i.
// ---------------------------------------------------------------------------
__global__ __launch_bounds__(512, 1) void rnn_scan(
    const float* __restrict__ Whh, const float* __restrict__ bhh,
    float* __restrict__ out, float* __restrict__ last) {
  __shared__ float part[8 * 512];          // 16 KB partials
  __shared__ unsigned short hbuf[512];     // 1 KB h state (f16)
  __shared__ unsigned int lds_pad[18432];  // 72 KB pad -> ~89 KB: 1 WG/CU

  const int b = blockIdx.x;
  const int t = threadIdx.x;
  const int kg = t >> 6;        // 0..7, wave-uniform
  const int hg = t & 63;
  const int k0 = kg * 64;
  if (b == 0x7fffffff) lds_pad[t] = 0;  // keep pad alive; never executes

  // --- one-time weight load: rows h = hg + 64*i, k in [k0, k0+64) ---
  unsigned int wreg[8][32];
#pragma unroll
  for (int i = 0; i < 8; ++i) {
    const float* wr = Whh + (size_t)(hg + 64 * i) * 512 + k0;
#pragma unroll
    for (int c4 = 0; c4 < 16; ++c4) {
      float4 f = ((const float4*)wr)[c4];
      wreg[i][c4 * 2]     = pack_h2(f.x, f.y);
      wreg[i][c4 * 2 + 1] = pack_h2(f.z, f.w);
    }
  }
  // pin the PACKED values: prevents remat of the load+cvt chain (R9 showed
  // remat costs ~2000 VALU cyc/step); forces clean scratch spill instead.
#pragma unroll
  for (int i = 0; i < 8; ++i)
#pragma unroll
    for (int d = 0; d < 32; ++d) asm volatile("" : "+v"(wreg[i][d]));

  if (t < 256) ((unsigned int*)hbuf)[t] = 0;  // h_0 = 0

  float* xt_row = out + (size_t)b * SS * HH;
  float xt_cur = xt_row[t];
  const float bh = bhh[t];
  const uint4* h4 = (const uint4*)hbuf + kg * 8;
  __syncthreads();

  for (int step = 0; step < SS; ++step) {
    // prefetch next xt (consumed next iteration; hides under dot phase)
    float xt_next = 0.f;
    if (step + 1 < SS) xt_next = xt_row[(size_t)(step + 1) * HH + t];

    // --- dot phase: a[i] = sum over k-span of W[hg+64i][k] * h[k] ---
    float a[8] = {0.f, 0.f, 0.f, 0.f, 0.f, 0.f, 0.f, 0.f};
#pragma unroll
    for (int c = 0; c < 8; ++c) {
      uint4 hv = h4[c];                      // broadcast (wave-uniform addr)
      a[0] = dot2a(wreg[0][4 * c + 0], hv.x, a[0]);
      a[0] = dot2a(wreg[0][4 * c + 1], hv.y, a[0]);
      a[0] = dot2a(wreg[0][4 * c + 2], hv.z, a[0]);
      a[0] = dot2a(wreg[0][4 * c + 3], hv.w, a[0]);
      a[1] = dot2a(wreg[1][4 * c + 0], hv.x, a[1]);
      a[1] = dot2a(wreg[1][4 * c + 1], hv.y, a[1]);
      a[1] = dot2a(wreg[1][4 * c + 2], hv.z, a[1]);
      a[1] = dot2a(wreg[1][4 * c + 3], hv.w, a[1]);
      a[2] = dot2a(wreg[2][4 * c + 0], hv.x, a[2]);
      a[2] = dot2a(wreg[2][4 * c + 1], hv.y, a[2]);
      a[2] = dot2a(wreg[2][4 * c + 2], hv.z, a[2]);
      a[2] = dot2a(wreg[2][4 * c + 3], hv.w, a[2]);
      a[3] = dot2a(wreg[3][4 * c + 0], hv.x, a[3]);
      a[3] = dot2a(wreg[3][4 * c + 1], hv.y, a[3]);
      a[3] = dot2a(wreg[3][4 * c + 2], hv.z, a[3]);
      a[3] = dot2a(wreg[3][4 * c + 3], hv.w, a[3]);
      a[4] = dot2a(wreg[4][4 * c + 0], hv.x, a[4]);
      a[4] = dot2a(wreg[4][4 * c + 1], hv.y, a[4]);
      a[4] = dot2a(wreg[4][4 * c + 2], hv.z, a[4]);
      a[4] = dot2a(wreg[4][4 * c + 3], hv.w, a[4]);
      a[5] = dot2a(wreg[5][4 * c + 0], hv.x, a[5]);
      a[5] = dot2a(wreg[5][4 * c + 1], hv.y, a[5]);
      a[5] = dot2a(wreg[5][4 * c + 2], hv.z, a[5]);
      a[5] = dot2a(wreg[5][4 * c + 3], hv.w, a[5]);
      a[6] = dot2a(wreg[6][4 * c + 0], hv.x, a[6]);
      a[6] = dot2a(wreg[6][4 * c + 1], hv.y, a[6]);
      a[6] = dot2a(wreg[6][4 * c + 2], hv.z, a[6]);
      a[6] = dot2a(wreg[6][4 * c + 3], hv.w, a[6]);
      a[7] = dot2a(wreg[7][4 * c + 0], hv.x, a[7]);
      a[7] = dot2a(wreg[7][4 * c + 1], hv.y, a[7]);
      a[7] = dot2a(wreg[7][4 * c + 2], hv.z, a[7]);
      a[7] = dot2a(wreg[7][4 * c + 3], hv.w, a[7]);
    }
    // partial store: within a wave lanes write consecutive dwords
#pragma unroll
    for (int i = 0; i < 8; ++i) part[kg * 512 + hg + 64 * i] = a[i];
    __syncthreads();

    // --- finalize: all 512 threads, h = t ---
    float y = xt_cur + bh;
#pragma unroll
    for (int g = 0; g < 8; ++g) y += part[g * 512 + t];
    float ht = tanhf(y);
    xt_row[(size_t)step * HH + t] = ht;  // overwrite xt with output h
    hbuf[t] = __builtin_bit_cast(unsigned short, (_Float16)ht);
    xt_cur = xt_next;
    __syncthreads();
  }

  // last = h_{S-1}: re-read the fp32 value just stored (L1/L2-hot)
  last[(size_t)b * HH + t] = xt_row[(size_t)(SS - 1) * HH + t];
}

extern "C" void kernel_launch(void* const* d_in, const int* in_sizes, int n_in,
                              void* d_out, int out_size, void* d_ws, size_t ws_size,
                              hipStream_t stream) {
  (void)in_sizes; (void)n_in; (void)d_ws; (void)ws_size; (void)out_size;
  const float* x   = (const float*)d_in[0];
  const float* Wih = (const float*)d_in[1];
  const float* bih = (const float*)d_in[2];
  const float* Whh = (const float*)d_in[3];
  const float* bhh = (const float*)d_in[4];
  float* out  = (float*)d_out;
  float* last = out + (size_t)BB * SS * HH;

  // Phase 1: input projection for all timesteps -> d_out (in-place xt buffer)
  xt_gemm<<<dim3(8, 1024), 256, 0, stream>>>(x, Wih, bih, out);

  // Phase 2: 64 sync-free per-batch chains, ~89 KB static LDS each
  rnn_scan<<<64, 512, 0, stream>>>(Whh, bhh, out, last);
}